// Round 3
// baseline (142.715 us; speedup 1.0000x reference)
//
#include <hip/hip_runtime.h>
#include <stdint.h>

#define BATCH 8
#define SEQ   2048
#define EMB   1024
#define HD    128

typedef __attribute__((ext_vector_type(8))) short  s8v;
typedef __attribute__((ext_vector_type(4))) float  f4v;

__device__ __forceinline__ ushort cvt_bf16(float f) {
    union { float f; uint32_t u; } v; v.f = f;
    uint32_t r = v.u + 0x7FFFu + ((v.u >> 16) & 1u);
    return (ushort)(r >> 16);
}

__device__ __forceinline__ uint32_t pack_bf16(float lo, float hi) {
    return ((uint32_t)cvt_bf16(hi) << 16) | (uint32_t)cvt_bf16(lo);
}

__device__ __forceinline__ f4v mfma16(s8v a, s8v b, f4v c) {
    return __builtin_amdgcn_mfma_f32_16x16x32_bf16(a, b, c, 0, 0, 0);
}

__device__ __forceinline__ uint32_t bperm(int idx, uint32_t v) {
    return (uint32_t)__builtin_amdgcn_ds_bpermute(idx, (int)v);
}

// ---------------- Stage 0: W -> bf16 concat [384][1024] ----------------------------
__global__ __launch_bounds__(256) void wcvt_kernel(
    const float* __restrict__ Wk, const float* __restrict__ Wq,
    const float* __restrict__ Wv, ushort* __restrict__ Wb)
{
    const int row = blockIdx.x;                 // 0..383
    const float* __restrict__ src =
        (row < 128) ? Wk + (size_t)row * EMB :
        (row < 256) ? Wq + (size_t)(row - 128) * EMB :
                      Wv + (size_t)(row - 256) * EMB;
    const int c = threadIdx.x << 2;
    float4 f = *(const float4*)(src + c);
    ushort4 h;
    h.x = cvt_bf16(f.x); h.y = cvt_bf16(f.y);
    h.z = cvt_bf16(f.z); h.w = cvt_bf16(f.w);
    *(ushort4*)(Wb + (size_t)row * EMB + c) = h;
}

// ---------------- Stage 1: fused QKV projection, single pass over x ----------------
// grid = 256 M-tiles of 64 rows. Block computes [64 x 384] (K|Q|V). 4 waves,
// wave tile 64m x 96n. BK=64.
__global__ __launch_bounds__(256) void qkv_kernel(
    const float* __restrict__ x,
    const ushort* __restrict__ Wb,
    ushort* __restrict__ Kg,     // [B*T][128] bf16
    ushort* __restrict__ Qg,     // [B*T][128] bf16
    ushort* __restrict__ VTg)    // [B][128][T] bf16 (transposed)
{
    const int m0 = blockIdx.x * 64;
    __shared__ ushort Al[64][68];     // x tile, +4 pad
    __shared__ ushort Bl[384][68];    // W tile (all 3), +4 pad

    const int tid  = threadIdx.x;
    const int lane = tid & 63;
    const int wave = tid >> 6;
    const int lr = lane & 15, lg = lane >> 4;

    f4v acc[4][6] = {};

    for (int k0 = 0; k0 < EMB; k0 += 64) {
        #pragma unroll
        for (int it = 0; it < 4; ++it) {
            int chunk = tid + 256 * it;               // 1024 chunks of 4 f32
            int r = chunk >> 4, c4 = (chunk & 15) << 2;
            float4 f = *(const float4*)(x + (size_t)(m0 + r) * EMB + k0 + c4);
            ushort4 h;
            h.x = cvt_bf16(f.x); h.y = cvt_bf16(f.y);
            h.z = cvt_bf16(f.z); h.w = cvt_bf16(f.w);
            *(ushort4*)&Al[r][c4] = h;
        }
        #pragma unroll
        for (int it = 0; it < 12; ++it) {
            int chunk = tid + 256 * it;               // 3072 chunks of 8 bf16
            int r = chunk >> 3, c8 = (chunk & 7) << 3;
            *(int4*)&Bl[r][c8] = *(const int4*)(Wb + (size_t)r * EMB + k0 + c8);
        }
        __syncthreads();
        #pragma unroll
        for (int kk = 0; kk < 2; ++kk) {
            s8v af[4], bf[6];
            #pragma unroll
            for (int i = 0; i < 4; ++i)
                af[i] = *(const s8v*)&Al[16 * i + lr][32 * kk + 8 * lg];
            #pragma unroll
            for (int j = 0; j < 6; ++j)
                bf[j] = *(const s8v*)&Bl[96 * wave + 16 * j + lr][32 * kk + 8 * lg];
            #pragma unroll
            for (int i = 0; i < 4; ++i)
                #pragma unroll
                for (int j = 0; j < 6; ++j)
                    acc[i][j] = mfma16(af[i], bf[j], acc[i][j]);
        }
        __syncthreads();
    }

    const int b  = m0 >> 11;          // batch
    const int tb = m0 & 2047;         // t within batch
    #pragma unroll
    for (int j = 0; j < 6; ++j) {
        const int n   = 96 * wave + 16 * j + lr;
        const int sel = n >> 7;       // 0:K 1:Q 2:V (uniform per wave,j)
        const int h   = n & 127;
        if (sel < 2) {
            ushort* __restrict__ outp = sel ? Qg : Kg;
            #pragma unroll
            for (int i = 0; i < 4; ++i)
                #pragma unroll
                for (int reg = 0; reg < 4; ++reg) {
                    int m = m0 + 16 * i + 4 * lg + reg;
                    outp[(size_t)m * HD + h] = cvt_bf16(acc[i][j][reg]);
                }
        } else {
            #pragma unroll
            for (int i = 0; i < 4; ++i) {
                int t = tb + 16 * i + 4 * lg;
                ushort4 hv;
                hv.x = cvt_bf16(acc[i][j][0]);
                hv.y = cvt_bf16(acc[i][j][1]);
                hv.z = cvt_bf16(acc[i][j][2]);
                hv.w = cvt_bf16(acc[i][j][3]);
                *(ushort4*)(VTg + ((size_t)b * HD + h) * SEQ + t) = hv;
            }
        }
    }
}

// ---------------- Stage 2: causal flash attention, split-KV, swapped QK^T ----------
// grid = (NCH, 32, 8). 4 waves x 16 q-rows; lane owns one q-row (replicated x4).
__global__ __launch_bounds__(256) void attn_kernel(
    const ushort* __restrict__ Qg,
    const ushort* __restrict__ Kg,
    const ushort* __restrict__ VTg,
    ushort* __restrict__ o_part,     // [B*32*NCH*64][128] bf16, unnormalized
    float2* __restrict__ ml_part,    // [B*32*NCH*64] (m,l)
    int CT, int NCH)
{
    const int ch = blockIdx.x;
    const int jq = blockIdx.y;
    const int b  = blockIdx.z;
    if (ch * CT > jq) return;
    const int t0 = ch * CT;
    const int t1 = min(t0 + CT, jq + 1);

    const int tid  = threadIdx.x;
    const int lane = tid & 63;
    const int wave = tid >> 6;
    const int lr = lane & 15, lg = lane >> 4;

    __shared__ ushort kl[64][132];    // K tile [s][d], +4 pad
    __shared__ ushort vl[128][68];    // V^T tile [h][s], +4 pad

    const ushort* __restrict__ Qb = Qg  + (size_t)b * SEQ * HD;
    const ushort* __restrict__ Kb = Kg  + (size_t)b * SEQ * HD;
    const ushort* __restrict__ Vb = VTg + (size_t)b * HD * SEQ;

    const int qw    = jq * 64 + wave * 16;
    const int q_abs = qw + lr;

    s8v qf[4];
    #pragma unroll
    for (int f = 0; f < 4; ++f)
        qf[f] = *(const s8v*)(Qb + (size_t)(qw + lr) * HD + 32 * f + 8 * lg);

    f4v o[8] = {};
    float m_r = -1e30f, l_r = 0.0f;

    // prologue: stage tile t0
    {
        const int s0 = t0 * 64;
        #pragma unroll
        for (int it = 0; it < 4; ++it) {
            int chunk = tid + 256 * it;
            int r = chunk >> 4, c8 = (chunk & 15) << 3;
            *(int4*)&kl[r][c8] = *(const int4*)(Kb + (size_t)(s0 + r) * HD + c8);
            int rh = chunk >> 3, cs = (chunk & 7) << 3;
            *(int4*)&vl[rh][cs] = *(const int4*)(Vb + (size_t)rh * SEQ + s0 + cs);
        }
        __syncthreads();
    }

    const int i0 = ((2 * (lg & 1)) * 16 + lr) << 2;        // bpermute byte idx
    const int i1 = ((2 * (lg & 1) + 1) * 16 + lr) << 2;
    const bool hi = (lg >= 2);

    for (int st = t0; st < t1; ++st) {
        const int s0 = st * 64;
        const bool more = (st + 1 < t1);

        // T14: issue next tile's loads early; LDS-write after the barrier
        int4 ks[4], vs[4];
        if (more) {
            const int sn = (st + 1) * 64;
            #pragma unroll
            for (int it = 0; it < 4; ++it) {
                int chunk = tid + 256 * it;
                int r = chunk >> 4, c8 = (chunk & 15) << 3;
                ks[it] = *(const int4*)(Kb + (size_t)(sn + r) * HD + c8);
                int rh = chunk >> 3, cs = (chunk & 7) << 3;
                vs[it] = *(const int4*)(Vb + (size_t)rh * SEQ + sn + cs);
            }
        }

        // QK^T (swapped): lane gets S[q=q_abs][s = s0+16sf+4lg+reg]
        f4v sc[4] = {};
        #pragma unroll
        for (int sf = 0; sf < 4; ++sf)
            #pragma unroll
            for (int kf = 0; kf < 4; ++kf) {
                s8v kfr = *(const s8v*)&kl[sf * 16 + lr][kf * 32 + 8 * lg];
                sc[sf] = mfma16(kfr, qf[kf], sc[sf]);
            }

        float p[4][4];
        const bool diag = (st == jq);
        #pragma unroll
        for (int sf = 0; sf < 4; ++sf)
            #pragma unroll
            for (int reg = 0; reg < 4; ++reg) {
                float v = sc[sf][reg] * 0.03125f;          // C^-0.5 = 1/32
                if (diag && (s0 + sf * 16 + 4 * lg + reg) > q_abs) v = -1e30f;
                p[sf][reg] = v;
            }

        // online softmax: in-lane (16 vals) + 2 shuffles across the 4 lg lanes
        float pm = p[0][0];
        #pragma unroll
        for (int sf = 0; sf < 4; ++sf)
            #pragma unroll
            for (int reg = 0; reg < 4; ++reg) pm = fmaxf(pm, p[sf][reg]);
        pm = fmaxf(pm, __shfl_xor(pm, 16));
        pm = fmaxf(pm, __shfl_xor(pm, 32));
        const float mnew = fmaxf(m_r, pm);
        const float fac  = __expf(m_r - mnew);
        m_r = mnew;

        float ls = 0.0f;
        #pragma unroll
        for (int sf = 0; sf < 4; ++sf)
            #pragma unroll
            for (int reg = 0; reg < 4; ++reg) {
                p[sf][reg] = __expf(p[sf][reg] - mnew);
                ls += p[sf][reg];
            }
        ls += __shfl_xor(ls, 16);
        ls += __shfl_xor(ls, 32);
        l_r = l_r * fac + ls;
        #pragma unroll
        for (int hf = 0; hf < 8; ++hf) o[hf] *= fac;

        // pack P to bf16 pairs; redistribute to PV B-fragments via bpermute
        uint32_t pk[4][2];
        #pragma unroll
        for (int sf = 0; sf < 4; ++sf) {
            pk[sf][0] = pack_bf16(p[sf][0], p[sf][1]);
            pk[sf][1] = pack_bf16(p[sf][2], p[sf][3]);
        }

        #pragma unroll
        for (int s2 = 0; s2 < 2; ++s2) {
            uint32_t a0 = bperm(i0, pk[2 * s2][0]);
            uint32_t a1 = bperm(i0, pk[2 * s2][1]);
            uint32_t a2 = bperm(i1, pk[2 * s2][0]);
            uint32_t a3 = bperm(i1, pk[2 * s2][1]);
            uint32_t b0 = bperm(i0, pk[2 * s2 + 1][0]);
            uint32_t b1 = bperm(i0, pk[2 * s2 + 1][1]);
            uint32_t b2 = bperm(i1, pk[2 * s2 + 1][0]);
            uint32_t b3 = bperm(i1, pk[2 * s2 + 1][1]);
            union { int4 i; s8v h; } pb;
            pb.i.x = (int)(hi ? b0 : a0);
            pb.i.y = (int)(hi ? b1 : a1);
            pb.i.z = (int)(hi ? b2 : a2);
            pb.i.w = (int)(hi ? b3 : a3);
            #pragma unroll
            for (int hf = 0; hf < 8; ++hf) {
                s8v vf = *(const s8v*)&vl[hf * 16 + lr][s2 * 32 + 8 * lg];
                o[hf] = mfma16(vf, pb.h, o[hf]);
            }
        }

        __syncthreads();                       // all waves done reading kl/vl
        if (more) {
            #pragma unroll
            for (int it = 0; it < 4; ++it) {
                int chunk = tid + 256 * it;
                int r = chunk >> 4, c8 = (chunk & 15) << 3;
                *(int4*)&kl[r][c8] = ks[it];
                int rh = chunk >> 3, cs = (chunk & 7) << 3;
                *(int4*)&vl[rh][cs] = vs[it];
            }
            __syncthreads();                   // writes visible
        }
    }

    // write unnormalized partial + (m,l)
    const size_t pbase = ((size_t)(b * 32 + jq) * NCH + ch) * 64;
    const int q = wave * 16 + lr;
    if (lg == 0) {
        float2 v; v.x = m_r; v.y = l_r;
        ml_part[pbase + q] = v;
    }
    #pragma unroll
    for (int hf = 0; hf < 8; ++hf) {
        ushort4 hv;
        hv.x = cvt_bf16(o[hf][0]);
        hv.y = cvt_bf16(o[hf][1]);
        hv.z = cvt_bf16(o[hf][2]);
        hv.w = cvt_bf16(o[hf][3]);
        *(ushort4*)(o_part + (pbase + q) * HD + hf * 16 + 4 * lg) = hv;
    }
}

// ---------------- Stage 3: combine partials ---------------------------------------
__global__ __launch_bounds__(256) void combine_kernel(
    const ushort* __restrict__ o_part,
    const float2* __restrict__ ml_part,
    float* __restrict__ out, int CT, int NCH)
{
    const int b  = blockIdx.x >> 5;
    const int jq = blockIdx.x & 31;
    const int nch = jq / CT + 1;
    const int tid = threadIdx.x;
    const int r  = tid >> 2;
    const int c0 = (tid & 3) << 5;

    const size_t mlbase = ((size_t)(b * 32 + jq) * NCH) * 64 + r;

    float M = -1e30f;
    for (int c = 0; c < nch; ++c)
        M = fmaxf(M, ml_part[mlbase + (size_t)c * 64].x);
    float L = 0.0f;
    for (int c = 0; c < nch; ++c) {
        float2 v = ml_part[mlbase + (size_t)c * 64];
        L += v.y * __expf(v.x - M);
    }
    const float invL = 1.0f / L;

    float acc[32];
    #pragma unroll
    for (int k = 0; k < 32; ++k) acc[k] = 0.0f;

    for (int c = 0; c < nch; ++c) {
        float2 v = ml_part[mlbase + (size_t)c * 64];
        float s = __expf(v.x - M) * invL;
        const ushort* op = o_part + (mlbase + (size_t)c * 64) * HD + c0;
        #pragma unroll
        for (int k8 = 0; k8 < 4; ++k8) {
            s8v pv = *(const s8v*)(op + k8 * 8);
            #pragma unroll
            for (int j = 0; j < 8; ++j) {
                union { uint32_t u; float f; } cv;
                cv.u = ((uint32_t)(ushort)pv[j]) << 16;
                acc[k8 * 8 + j] += cv.f * s;
            }
        }
    }

    float* po = out + ((size_t)b * SEQ + jq * 64 + r) * HD + c0;
    #pragma unroll
    for (int k4 = 0; k4 < 8; ++k4)
        *(float4*)(po + k4 * 4) = make_float4(acc[k4 * 4], acc[k4 * 4 + 1],
                                              acc[k4 * 4 + 2], acc[k4 * 4 + 3]);
}

extern "C" void kernel_launch(void* const* d_in, const int* in_sizes, int n_in,
                              void* d_out, int out_size, void* d_ws, size_t ws_size,
                              hipStream_t stream) {
    const float* x  = (const float*)d_in[0];
    const float* Wk = (const float*)d_in[1];
    const float* Wq = (const float*)d_in[2];
    const float* Wv = (const float*)d_in[3];

    const size_t qkv_elems = (size_t)BATCH * SEQ * HD;   // 2,097,152
    const size_t wb_elems  = (size_t)384 * EMB;          // 393,216
    ushort* Kg  = (ushort*)d_ws;
    ushort* Qg  = Kg + qkv_elems;
    ushort* VTg = Qg + qkv_elems;
    float*  outp = (float*)d_out;

    int CT = 4, NCH = 8;
    {
        size_t rows = (size_t)BATCH * 32 * NCH * 64;
        size_t need = 3 * qkv_elems * sizeof(ushort)
                    + rows * (HD * sizeof(ushort) + sizeof(float2))
                    + wb_elems * sizeof(ushort);
        if (ws_size < need) { CT = 8; NCH = 4; }
    }
    size_t part_rows = (size_t)BATCH * 32 * NCH * 64;
    ushort* o_part  = VTg + qkv_elems;
    float2* ml_part = (float2*)(o_part + part_rows * HD);
    ushort* Wb      = (ushort*)(ml_part + part_rows);

    wcvt_kernel<<<384, 256, 0, stream>>>(Wk, Wq, Wv, Wb);
    qkv_kernel<<<256, 256, 0, stream>>>(x, Wb, Kg, Qg, VTg);
    dim3 g2(NCH, 32, BATCH);
    attn_kernel<<<g2, 256, 0, stream>>>(Qg, Kg, VTg, o_part, ml_part, CT, NCH);
    combine_kernel<<<256, 256, 0, stream>>>(o_part, ml_part, outp, CT, NCH);
}

// Round 4
// 81.970 us; speedup vs baseline: 1.7411x; 1.7411x over previous
//
#include <hip/hip_runtime.h>
#include <stdint.h>

#define BATCH 8
#define SEQ   2048
#define EMB   1024
#define HD    128

typedef __attribute__((ext_vector_type(8))) short  s8v;
typedef __attribute__((ext_vector_type(4))) float  f4v;

__device__ __forceinline__ ushort cvt_bf16(float f) {
    union { float f; uint32_t u; } v; v.f = f;
    uint32_t r = v.u + 0x7FFFu + ((v.u >> 16) & 1u);
    return (ushort)(r >> 16);
}

__device__ __forceinline__ uint32_t pack_bf16(float lo, float hi) {
    return ((uint32_t)cvt_bf16(hi) << 16) | (uint32_t)cvt_bf16(lo);
}

__device__ __forceinline__ f4v mfma16(s8v a, s8v b, f4v c) {
    return __builtin_amdgcn_mfma_f32_16x16x32_bf16(a, b, c, 0, 0, 0);
}

__device__ __forceinline__ uint32_t bperm(int idx, uint32_t v) {
    return (uint32_t)__builtin_amdgcn_ds_bpermute(idx, (int)v);
}

// async global->LDS DMA, 16B per lane; LDS dest = wave-uniform base + lane*16
__device__ __forceinline__ void gl_lds16(const void* g, void* l) {
    __builtin_amdgcn_global_load_lds(
        (const __attribute__((address_space(1))) void*)g,
        (__attribute__((address_space(3))) void*)l, 16, 0, 0);
}

// ---------------- Stage 0: W -> bf16 concat [384][1024] ----------------------------
__global__ __launch_bounds__(256) void wcvt_kernel(
    const float* __restrict__ Wk, const float* __restrict__ Wq,
    const float* __restrict__ Wv, ushort* __restrict__ Wb)
{
    const int row = blockIdx.x;                 // 0..383
    const float* __restrict__ src =
        (row < 128) ? Wk + (size_t)row * EMB :
        (row < 256) ? Wq + (size_t)(row - 128) * EMB :
                      Wv + (size_t)(row - 256) * EMB;
    const int c = threadIdx.x << 2;
    float4 f = *(const float4*)(src + c);
    ushort4 h;
    h.x = cvt_bf16(f.x); h.y = cvt_bf16(f.y);
    h.z = cvt_bf16(f.z); h.w = cvt_bf16(f.w);
    *(ushort4*)(Wb + (size_t)row * EMB + c) = h;
}

// ---------------- Stage 1: fused QKV projection ------------------------------------
// grid = 512 M-tiles of 32 rows. Block computes [32 x 384] (K|Q|V). 4 waves,
// wave tile 32m x 96n. BK=64. W staged via swizzled global_load_lds.
__global__ __launch_bounds__(256) void qkv_kernel(
    const float* __restrict__ x,
    const ushort* __restrict__ Wb,
    ushort* __restrict__ Kg,     // [B*T][128] bf16
    ushort* __restrict__ Qg,     // [B*T][128] bf16
    ushort* __restrict__ VTg)    // [B][128][T] bf16 (transposed)
{
    const int m0 = blockIdx.x * 32;
    __shared__ ushort Al[32][68];      // x tile (padded, VALU-staged: needs f32->bf16)
    __shared__ ushort Bl[384 * 64];    // W tile, linear + XOR-swizzled storage

    const int tid  = threadIdx.x;
    const int lane = tid & 63;
    const int wave = tid >> 6;
    const int lr = lane & 15, lg = lane >> 4;
    const int xsw = (lr & 7) << 4;

    f4v acc[2][6] = {};

    // W staging: 48 KB / tile-step = 48 calls of 1KB; 12 per wave.
    // LDS slot byte L = cc*1024 + lane*16 -> row = L>>7, col = (L&127)^((row&7)<<4)
    const char* gW[12];
    #pragma unroll
    for (int c = 0; c < 12; ++c) {
        int cc   = wave * 12 + c;
        int row  = cc * 8 + (lane >> 3);
        int colb = ((lane & 7) << 4) ^ ((row & 7) << 4);
        gW[c] = (const char*)Wb + (size_t)row * (EMB * 2) + colb;
    }
    const int ar = tid >> 3, ac = (tid & 7) << 3;     // x stage: row, col8
    const float* xp = x + (size_t)(m0 + ar) * EMB + ac;

    for (int k0 = 0; k0 < EMB; k0 += 64) {
        #pragma unroll
        for (int c = 0; c < 12; ++c) {               // issue W DMA first
            gl_lds16(gW[c], (char*)Bl + ((wave * 12 + c) << 10));
            gW[c] += 128;                            // advance 64 cols * 2B
        }
        float4 f0 = *(const float4*)(xp);
        float4 f1 = *(const float4*)(xp + 4);
        xp += 64;
        ushort4 h0, h1;
        h0.x = cvt_bf16(f0.x); h0.y = cvt_bf16(f0.y);
        h0.z = cvt_bf16(f0.z); h0.w = cvt_bf16(f0.w);
        h1.x = cvt_bf16(f1.x); h1.y = cvt_bf16(f1.y);
        h1.z = cvt_bf16(f1.z); h1.w = cvt_bf16(f1.w);
        *(ushort4*)&Al[ar][ac]     = h0;
        *(ushort4*)&Al[ar][ac + 4] = h1;
        __syncthreads();                             // drains DMA (vmcnt) + ds_writes

        #pragma unroll
        for (int kk = 0; kk < 2; ++kk) {
            s8v af[2], bf[6];
            #pragma unroll
            for (int i = 0; i < 2; ++i)
                af[i] = *(const s8v*)&Al[16 * i + lr][32 * kk + 8 * lg];
            #pragma unroll
            for (int j = 0; j < 6; ++j) {
                int row = 96 * wave + 16 * j + lr;   // row&7 == lr&7
                bf[j] = *(const s8v*)((const char*)Bl + (row << 7)
                                      + ((kk * 64 + lg * 16) ^ xsw));
            }
            #pragma unroll
            for (int i = 0; i < 2; ++i)
                #pragma unroll
                for (int j = 0; j < 6; ++j)
                    acc[i][j] = mfma16(af[i], bf[j], acc[i][j]);
        }
        __syncthreads();
    }

    const int b  = m0 >> 11;
    const int tb = m0 & 2047;
    #pragma unroll
    for (int j = 0; j < 6; ++j) {
        const int n   = 96 * wave + 16 * j + lr;
        const int sel = n >> 7;                      // 0:K 1:Q 2:V
        const int h   = n & 127;
        if (sel < 2) {
            ushort* __restrict__ outp = sel ? Qg : Kg;
            #pragma unroll
            for (int i = 0; i < 2; ++i)
                #pragma unroll
                for (int reg = 0; reg < 4; ++reg) {
                    int m = m0 + 16 * i + 4 * lg + reg;
                    outp[(size_t)m * HD + h] = cvt_bf16(acc[i][j][reg]);
                }
        } else {
            #pragma unroll
            for (int i = 0; i < 2; ++i) {
                int t = tb + 16 * i + 4 * lg;
                ushort4 hv;
                hv.x = cvt_bf16(acc[i][j][0]);
                hv.y = cvt_bf16(acc[i][j][1]);
                hv.z = cvt_bf16(acc[i][j][2]);
                hv.w = cvt_bf16(acc[i][j][3]);
                *(ushort4*)(VTg + ((size_t)b * HD + h) * SEQ + t) = hv;
            }
        }
    }
}

// ---------------- Stage 2: flash attention, split-KV, dbuf gload_lds ---------------
// grid = (tri_slots, BATCH). Exact triangular decomposition; no dead blocks.
// Double-buffered K/V via global_load_lds + XOR swizzle; 1 barrier per tile.
__global__ __launch_bounds__(256) void attn_kernel(
    const ushort* __restrict__ Qg,
    const ushort* __restrict__ Kg,
    const ushort* __restrict__ VTg,
    ushort* __restrict__ o_part,     // [B*32*NCH*64][128] bf16, unnormalized
    float2* __restrict__ ml_part,    // [B*32*NCH*64] (m,l)
    int cts, int NCH)
{
    // decode triangular slot -> (jq, ch)
    int s = blockIdx.x, g = 0;
    while (s >= ((g + 1) << cts)) { s -= (g + 1) << cts; ++g; }
    int q2 = 0;
    while (s >= g + 1) { s -= g + 1; ++q2; }
    const int jq = (g << cts) + q2;
    const int ch = s;
    const int b  = blockIdx.y;
    const int t0 = ch << cts;
    const int t1 = min(t0 + (1 << cts), jq + 1);

    const int tid  = threadIdx.x;
    const int lane = tid & 63;
    const int wave = tid >> 6;
    const int lr = lane & 15, lg = lane >> 4;
    const int xsw = (lr & 7) << 4;

    __shared__ ushort kl[2][64 * 128];   // [s][d] linear, swizzled storage
    __shared__ ushort vl[2][128 * 64];   // [h][s] linear, swizzled storage

    const ushort* __restrict__ Qb = Qg  + (size_t)b * SEQ * HD;
    const ushort* __restrict__ Kb = Kg  + (size_t)b * SEQ * HD;
    const ushort* __restrict__ Vb = VTg + (size_t)b * HD * SEQ;

    // staging source pointers (inverse-swizzled so linear DMA lands swizzled)
    const char* gK[4];
    const char* gV[4];
    #pragma unroll
    for (int c = 0; c < 4; ++c) {
        int cc = wave * 4 + c;
        {   int row  = cc * 4 + (lane >> 4);                 // K: 4 rows/call
            int colb = ((lane & 15) << 4) ^ ((row & 7) << 4);
            gK[c] = (const char*)Kb + (size_t)(t0 * 64 + row) * 256 + colb; }
        {   int row  = cc * 8 + (lane >> 3);                 // V: 8 rows/call
            int colb = ((lane & 7) << 4) ^ ((row & 7) << 4);
            gV[c] = (const char*)Vb + (size_t)row * (SEQ * 2)
                    + (size_t)t0 * 128 + colb; }
    }

    const int qw    = jq * 64 + wave * 16;
    const int q_abs = qw + lr;

    s8v qf[4];
    #pragma unroll
    for (int f = 0; f < 4; ++f)
        qf[f] = *(const s8v*)(Qb + (size_t)(qw + lr) * HD + 32 * f + 8 * lg);

    f4v o[8] = {};
    float m_r = -1e30f, l_r = 0.0f;

    // prologue: stage tile t0 into buf 0
    #pragma unroll
    for (int c = 0; c < 4; ++c) {
        gl_lds16(gK[c], (char*)(&kl[0][0]) + ((wave * 4 + c) << 10));
        gl_lds16(gV[c], (char*)(&vl[0][0]) + ((wave * 4 + c) << 10));
        gK[c] += 64 * 256;
        gV[c] += 128;
    }
    __syncthreads();

    const int i0 = ((2 * (lg & 1)) * 16 + lr) << 2;
    const int i1 = ((2 * (lg & 1) + 1) * 16 + lr) << 2;
    const bool hi = (lg >= 2);

    int cur = 0;
    for (int st = t0; st < t1; ++st) {
        if (st + 1 < t1) {                       // issue next-tile DMA (T3/T4)
            char* kb = (char*)(&kl[cur ^ 1][0]);
            char* vb = (char*)(&vl[cur ^ 1][0]);
            #pragma unroll
            for (int c = 0; c < 4; ++c) {
                gl_lds16(gK[c], kb + ((wave * 4 + c) << 10));
                gl_lds16(gV[c], vb + ((wave * 4 + c) << 10));
                gK[c] += 64 * 256;
                gV[c] += 128;
            }
        }
        const int s0 = st * 64;
        const char* klb = (const char*)(&kl[cur][0]);
        const char* vlb = (const char*)(&vl[cur][0]);

        // QK^T (swapped): lane owns q-col q_abs, holds s rows
        f4v sc[4] = {};
        #pragma unroll
        for (int sf = 0; sf < 4; ++sf)
            #pragma unroll
            for (int kf = 0; kf < 4; ++kf) {
                s8v kfr = *(const s8v*)(klb + ((sf * 16 + lr) << 8)
                                        + ((kf * 64 + lg * 16) ^ xsw));
                sc[sf] = mfma16(kfr, qf[kf], sc[sf]);
            }

        float p[4][4];
        const bool diag = (st == jq);
        #pragma unroll
        for (int sf = 0; sf < 4; ++sf)
            #pragma unroll
            for (int reg = 0; reg < 4; ++reg) {
                float v = sc[sf][reg] * 0.03125f;          // C^-0.5 = 1/32
                if (diag && (s0 + sf * 16 + 4 * lg + reg) > q_abs) v = -1e30f;
                p[sf][reg] = v;
            }

        // online softmax: in-lane (16) + 2 shuffles across lg quads
        float pm = p[0][0];
        #pragma unroll
        for (int sf = 0; sf < 4; ++sf)
            #pragma unroll
            for (int reg = 0; reg < 4; ++reg) pm = fmaxf(pm, p[sf][reg]);
        pm = fmaxf(pm, __shfl_xor(pm, 16));
        pm = fmaxf(pm, __shfl_xor(pm, 32));
        const float mnew = fmaxf(m_r, pm);
        const float fac  = __expf(m_r - mnew);
        m_r = mnew;

        float ls = 0.0f;
        #pragma unroll
        for (int sf = 0; sf < 4; ++sf)
            #pragma unroll
            for (int reg = 0; reg < 4; ++reg) {
                p[sf][reg] = __expf(p[sf][reg] - mnew);
                ls += p[sf][reg];
            }
        ls += __shfl_xor(ls, 16);
        ls += __shfl_xor(ls, 32);
        l_r = l_r * fac + ls;
        #pragma unroll
        for (int hf = 0; hf < 8; ++hf) o[hf] *= fac;

        // pack P -> bf16 pairs; redistribute to PV B-fragments via bpermute
        uint32_t pk[4][2];
        #pragma unroll
        for (int sf = 0; sf < 4; ++sf) {
            pk[sf][0] = pack_bf16(p[sf][0], p[sf][1]);
            pk[sf][1] = pack_bf16(p[sf][2], p[sf][3]);
        }

        #pragma unroll
        for (int s2 = 0; s2 < 2; ++s2) {
            uint32_t a0 = bperm(i0, pk[2 * s2][0]);
            uint32_t a1 = bperm(i0, pk[2 * s2][1]);
            uint32_t a2 = bperm(i1, pk[2 * s2][0]);
            uint32_t a3 = bperm(i1, pk[2 * s2][1]);
            uint32_t b0 = bperm(i0, pk[2 * s2 + 1][0]);
            uint32_t b1 = bperm(i0, pk[2 * s2 + 1][1]);
            uint32_t b2 = bperm(i1, pk[2 * s2 + 1][0]);
            uint32_t b3 = bperm(i1, pk[2 * s2 + 1][1]);
            union { int4 i; s8v h; } pb;
            pb.i.x = (int)(hi ? b0 : a0);
            pb.i.y = (int)(hi ? b1 : a1);
            pb.i.z = (int)(hi ? b2 : a2);
            pb.i.w = (int)(hi ? b3 : a3);
            #pragma unroll
            for (int hf = 0; hf < 8; ++hf) {
                s8v vf = *(const s8v*)(vlb + ((hf * 16 + lr) << 7)
                                       + ((s2 * 64 + lg * 16) ^ xsw));
                o[hf] = mfma16(vf, pb.h, o[hf]);
            }
        }

        __syncthreads();     // drains next-tile DMA (vmcnt) + all LDS reads
        cur ^= 1;
    }

    // write unnormalized partial + (m,l)
    const size_t pbase = ((size_t)(b * 32 + jq) * NCH + ch) * 64;
    const int q = wave * 16 + lr;
    if (lg == 0) {
        float2 v; v.x = m_r; v.y = l_r;
        ml_part[pbase + q] = v;
    }
    #pragma unroll
    for (int hf = 0; hf < 8; ++hf) {
        ushort4 hv;
        hv.x = cvt_bf16(o[hf][0]);
        hv.y = cvt_bf16(o[hf][1]);
        hv.z = cvt_bf16(o[hf][2]);
        hv.w = cvt_bf16(o[hf][3]);
        *(ushort4*)(o_part + (pbase + q) * HD + hf * 16 + 4 * lg) = hv;
    }
}

// ---------------- Stage 3: combine partials ---------------------------------------
// grid = 1024; block = 16 rows x 16 lanes/row (8 cols each).
__global__ __launch_bounds__(256) void combine_kernel(
    const ushort* __restrict__ o_part,
    const float2* __restrict__ ml_part,
    float* __restrict__ out, int cts, int NCH)
{
    const int tid = threadIdx.x;
    const int R   = blockIdx.x * 16 + (tid >> 4);    // global q-row 0..16383
    const int c16 = tid & 15;
    const int b  = R >> 11;
    const int rq = R & 2047;
    const int jq = rq >> 6;
    const int r  = rq & 63;
    const int nch = (jq >> cts) + 1;

    const size_t mlbase = ((size_t)(b * 32 + jq) * NCH) * 64 + r;

    float M = -1e30f;
    for (int c = 0; c < nch; ++c)
        M = fmaxf(M, ml_part[mlbase + (size_t)c * 64].x);
    float L = 0.0f;
    for (int c = 0; c < nch; ++c) {
        float2 v = ml_part[mlbase + (size_t)c * 64];
        L += v.y * __expf(v.x - M);
    }
    const float invL = 1.0f / L;

    float acc[8];
    #pragma unroll
    for (int k = 0; k < 8; ++k) acc[k] = 0.0f;

    for (int c = 0; c < nch; ++c) {
        float2 v = ml_part[mlbase + (size_t)c * 64];
        float sc = __expf(v.x - M) * invL;
        s8v pv = *(const s8v*)(o_part + (mlbase + (size_t)c * 64) * HD + c16 * 8);
        #pragma unroll
        for (int j = 0; j < 8; ++j) {
            union { uint32_t u; float f; } cv;
            cv.u = ((uint32_t)(ushort)pv[j]) << 16;
            acc[j] += cv.f * sc;
        }
    }

    float* po = out + (size_t)R * HD + c16 * 8;
    *(float4*)(po)     = make_float4(acc[0], acc[1], acc[2], acc[3]);
    *(float4*)(po + 4) = make_float4(acc[4], acc[5], acc[6], acc[7]);
}

extern "C" void kernel_launch(void* const* d_in, const int* in_sizes, int n_in,
                              void* d_out, int out_size, void* d_ws, size_t ws_size,
                              hipStream_t stream) {
    const float* x  = (const float*)d_in[0];
    const float* Wk = (const float*)d_in[1];
    const float* Wq = (const float*)d_in[2];
    const float* Wv = (const float*)d_in[3];

    const size_t qkv_elems = (size_t)BATCH * SEQ * HD;   // 2,097,152
    const size_t wb_elems  = (size_t)384 * EMB;          // 393,216
    ushort* Kg  = (ushort*)d_ws;
    ushort* Qg  = Kg + qkv_elems;
    ushort* VTg = Qg + qkv_elems;
    float*  outp = (float*)d_out;

    int cts = 2, NCH = 8;     // chunk = 4 kv-tiles (256 cols)
    {
        size_t rows = (size_t)BATCH * 32 * NCH * 64;
        size_t need = 3 * qkv_elems * sizeof(ushort)
                    + rows * (HD * sizeof(ushort) + sizeof(float2))
                    + wb_elems * sizeof(ushort);
        if (ws_size < need) { cts = 3; NCH = 4; }
    }
    size_t part_rows = (size_t)BATCH * 32 * NCH * 64;
    ushort* o_part  = VTg + qkv_elems;
    float2* ml_part = (float2*)(o_part + part_rows * HD);
    ushort* Wb      = (ushort*)(ml_part + part_rows);

    // triangular slot count: G groups of (1<<cts) jq's, group g has g+1 chunks
    const int G = 32 >> cts;
    const int slots = (1 << cts) * G * (G + 1) / 2;      // 144 (cts=2) / 80 (cts=3)

    wcvt_kernel<<<384, 256, 0, stream>>>(Wk, Wq, Wv, Wb);
    qkv_kernel<<<512, 256, 0, stream>>>(x, Wb, Kg, Qg, VTg);
    dim3 g2(slots, BATCH);
    attn_kernel<<<g2, 256, 0, stream>>>(Qg, Kg, VTg, o_part, ml_part, cts, NCH);
    combine_kernel<<<1024, 256, 0, stream>>>(o_part, ml_part, outp, cts, NCH);
}